// Round 7
// baseline (628.287 us; speedup 1.0000x reference)
//
#include <hip/hip_runtime.h>

#define NNODES 100000
#define NEDGES 1600000
#define HDIM 64
#define SCAN_BS 512
#define NBLK_SCAN ((NNODES + SCAN_BS - 1) / SCAN_BS)   // 196
#define NPART 8
#define PRANGE 12500   // NNODES / NPART exactly

// ---------- bf16x2 pack/unpack (RNE pack; exact unpack) ----------
__device__ inline unsigned pack_bf16x2(float a, float b) {
    union { float f; unsigned u; } ua, ub;
    ua.f = a; ub.f = b;
    unsigned ra = (ua.u + 0x7FFFu + ((ua.u >> 16) & 1u)) >> 16;
    unsigned rb = (ub.u + 0x7FFFu + ((ub.u >> 16) & 1u)) >> 16;
    return ra | (rb << 16);
}
__device__ inline float2 unpack_bf16x2(unsigned p) {
    union { unsigned u; float f; } a, b;
    a.u = p << 16;
    b.u = p & 0xFFFF0000u;
    return make_float2(a.f, b.f);
}

// ---------- non-temporal helpers (HIP vector structs aren't builtin-compatible) ----------
__device__ inline int2 nt_load_int2(const int2* p) {
    unsigned long long v = __builtin_nontemporal_load((const unsigned long long*)p);
    int2 r; r.x = (int)(unsigned)(v & 0xFFFFFFFFull); r.y = (int)(unsigned)(v >> 32);
    return r;
}
__device__ inline void nt_store_f2(float* p, float a, float b) {
    unsigned long long v = ((unsigned long long)__float_as_uint(b) << 32) |
                           (unsigned long long)__float_as_uint(a);
    __builtin_nontemporal_store(v, (unsigned long long*)p);
}

// ---------------- CSR build: histogram (4 edges/thread) ----------------
__global__ void hist4(const int4* __restrict__ src4, const int4* __restrict__ dst4,
                      int* cnt_s, int* cnt_d, int ne4) {
    int i = blockIdx.x * blockDim.x + threadIdx.x;
    if (i >= ne4) return;
    int4 s = src4[i], d = dst4[i];
    atomicAdd(&cnt_s[s.x], 1); atomicAdd(&cnt_s[s.y], 1);
    atomicAdd(&cnt_s[s.z], 1); atomicAdd(&cnt_s[s.w], 1);
    atomicAdd(&cnt_d[d.x], 1); atomicAdd(&cnt_d[d.y], 1);
    atomicAdd(&cnt_d[d.z], 1); atomicAdd(&cnt_d[d.w], 1);
}

__global__ void make_dinv(const int* __restrict__ cnt_d, float* dinv, int n) {
    int i = blockIdx.x * blockDim.x + threadIdx.x;
    if (i < n) dinv[i] = rsqrtf((float)(cnt_d[i] + 1));   // +1 self-loop
}

// ---------------- CSR build: 2-level exclusive scan ----------------
__global__ void scan1(const int* __restrict__ cnt, int* rp, int* bsum, int n) {
    __shared__ int temp[SCAN_BS];
    int tid = threadIdx.x;
    int i = blockIdx.x * SCAN_BS + tid;
    int v = (i < n) ? cnt[i] : 0;
    temp[tid] = v;
    __syncthreads();
    for (int off = 1; off < SCAN_BS; off <<= 1) {
        int t = (tid >= off) ? temp[tid - off] : 0;
        __syncthreads();
        temp[tid] += t;
        __syncthreads();
    }
    int inc = temp[tid];
    if (i < n) rp[i] = inc - v;
    if (tid == SCAN_BS - 1) bsum[blockIdx.x] = inc;
}

__global__ void scan2(const int* __restrict__ bsum, int* boff, int nb) {
    __shared__ int temp[256];
    int tid = threadIdx.x;
    int v = (tid < nb) ? bsum[tid] : 0;
    temp[tid] = v;
    __syncthreads();
    for (int off = 1; off < 256; off <<= 1) {
        int t = (tid >= off) ? temp[tid - off] : 0;
        __syncthreads();
        temp[tid] += t;
        __syncthreads();
    }
    if (tid < nb) boff[tid] = temp[tid] - v;
}

__global__ void scan3(int* rp, int* cur, const int* __restrict__ boff, int n, int total) {
    int i = blockIdx.x * blockDim.x + threadIdx.x;
    if (i < n) {
        int v = rp[i] + boff[i / SCAN_BS];
        rp[i] = v;
        cur[i] = v;
    }
    if (i == 0) rp[n] = total;
}

// ---------------- CSR fill, XCD-partitioned scatter ----------------
// Edge stream read with nt (evict-first) so the CSR write lines keep L2.
// dst-CSR payload: (src, dinv[src]);  src-CSR payload: (dst, adjv)
__global__ void fill_csr_part(const int* __restrict__ src, const int* __restrict__ dst,
                              const float* __restrict__ adjv, const float* __restrict__ dinv,
                              int* cur_d, int* cur_s,
                              int2* __restrict__ csr_d, int2* __restrict__ csr_s, int ne) {
    int part = blockIdx.x & (NPART - 1);
    int blk  = blockIdx.x >> 3;
    int nblk = gridDim.x >> 3;
    int lo = part * PRANGE;
    for (int i = blk * blockDim.x + threadIdx.x; i < ne; i += nblk * blockDim.x) {
        int s = __builtin_nontemporal_load(&src[i]);
        int d = __builtin_nontemporal_load(&dst[i]);
        if ((unsigned)(d - lo) < PRANGE) {
            int2 pd; pd.x = s; pd.y = __float_as_int(dinv[s]);
            int p = atomicAdd(&cur_d[d], 1);
            csr_d[p] = pd;
        }
        if ((unsigned)(s - lo) < PRANGE) {
            float av = __builtin_nontemporal_load(&adjv[i]);
            int2 ps; ps.x = d; ps.y = __float_as_int(av);
            int q = atomicAdd(&cur_s[s], 1);
            csr_s[q] = ps;
        }
    }
}

// ---------------- GEMM [n,64]@[64,64] -> f32 (+bias, optional relu) ----------------
__global__ void gemm64(const float* __restrict__ X, const float* __restrict__ W,
                       const float* __restrict__ bias, float* __restrict__ Y,
                       int n, int do_relu) {
    __shared__ float Ws[HDIM * HDIM];
    __shared__ float xs[16][68];
    int tid = threadIdx.x;
    for (int i = tid; i < HDIM * HDIM; i += 256) Ws[i] = W[i];
    int q = tid & 15;
    int rl = tid >> 4;
    float4 bc = bias ? *(const float4*)&bias[4 * q] : make_float4(0.f, 0.f, 0.f, 0.f);
    __syncthreads();
    for (int r0 = blockIdx.x * 16; r0 < n; r0 += gridDim.x * 16) {
        int r = r0 + rl;
        if (r < n) {
            *(float4*)&xs[rl][4 * q] = *(const float4*)&X[(size_t)r * HDIM + 4 * q];
            float4 acc = bc;
#pragma unroll
            for (int k = 0; k < HDIM; ++k) {
                float xk = xs[rl][k];
                float4 w4 = *(const float4*)&Ws[k * HDIM + 4 * q];
                acc.x += xk * w4.x; acc.y += xk * w4.y;
                acc.z += xk * w4.z; acc.w += xk * w4.w;
            }
            if (do_relu) {
                acc.x = fmaxf(acc.x, 0.f); acc.y = fmaxf(acc.y, 0.f);
                acc.z = fmaxf(acc.z, 0.f); acc.w = fmaxf(acc.w, 0.f);
            }
            *(float4*)&Y[(size_t)r * HDIM + 4 * q] = acc;
        }
    }
}

// ---------------- GEMM [n,64]@[64,64] -> packed bf16x2 out ----------------
__global__ void gemm64p(const float* __restrict__ X, const float* __restrict__ W,
                        unsigned* __restrict__ Yp, int n) {
    __shared__ float Ws[HDIM * HDIM];
    __shared__ float xs[16][68];
    int tid = threadIdx.x;
    for (int i = tid; i < HDIM * HDIM; i += 256) Ws[i] = W[i];
    int q = tid & 15;
    int rl = tid >> 4;
    __syncthreads();
    for (int r0 = blockIdx.x * 16; r0 < n; r0 += gridDim.x * 16) {
        int r = r0 + rl;
        if (r < n) {
            *(float4*)&xs[rl][4 * q] = *(const float4*)&X[(size_t)r * HDIM + 4 * q];
            float4 acc = make_float4(0.f, 0.f, 0.f, 0.f);
#pragma unroll
            for (int k = 0; k < HDIM; ++k) {
                float xk = xs[rl][k];
                float4 w4 = *(const float4*)&Ws[k * HDIM + 4 * q];
                acc.x += xk * w4.x; acc.y += xk * w4.y;
                acc.z += xk * w4.z; acc.w += xk * w4.w;
            }
            uint2 pv;
            pv.x = pack_bf16x2(acc.x, acc.y);
            pv.y = pack_bf16x2(acc.z, acc.w);
            *(uint2*)&Yp[(size_t)r * 32 + 2 * q] = pv;
        }
    }
}

// ---------------- fused GCN gather + bias + LN + ReLU ----------------
// half-wave (32 lanes) per node; 8-wide unrolled edge loop; csr stream nt,
// xwp (hot random-reuse set) default-cached, h written nt.
__global__ void conv_ln(const unsigned* __restrict__ xwp, const int* __restrict__ rp,
                        const int2* __restrict__ csr, const float* __restrict__ dinv,
                        const float* __restrict__ cb, const float* __restrict__ g,
                        const float* __restrict__ b, float* __restrict__ h, int n) {
    int gid = blockIdx.x * blockDim.x + threadIdx.x;
    int node = gid >> 5;
    if (node >= n) return;
    int c2 = gid & 31;
    int wl = threadIdx.x & 63;
    int hb = wl & 32;
    int e0 = rp[node], e1 = rp[node + 1];
    float di = dinv[node];
    float2 self = unpack_bf16x2(xwp[(size_t)node * 32 + c2]);
    float acc0 = self.x * di, acc1 = self.y * di;
    for (int j0 = e0; j0 < e1; j0 += 32) {
        int jj = j0 + c2;
        int sidx = 0; float dv = 0.0f;
        if (jj < e1) { int2 pl = nt_load_int2(&csr[jj]); sidx = pl.x; dv = __int_as_float(pl.y); }
        int cnt = min(32, e1 - j0);
        int k = 0;
        for (; k + 8 <= cnt; k += 8) {
            int sv0 = __shfl(sidx, hb | k);       float f0 = __shfl(dv, hb | k);
            int sv1 = __shfl(sidx, hb | (k + 1)); float f1 = __shfl(dv, hb | (k + 1));
            int sv2 = __shfl(sidx, hb | (k + 2)); float f2 = __shfl(dv, hb | (k + 2));
            int sv3 = __shfl(sidx, hb | (k + 3)); float f3 = __shfl(dv, hb | (k + 3));
            int sv4 = __shfl(sidx, hb | (k + 4)); float f4 = __shfl(dv, hb | (k + 4));
            int sv5 = __shfl(sidx, hb | (k + 5)); float f5 = __shfl(dv, hb | (k + 5));
            int sv6 = __shfl(sidx, hb | (k + 6)); float f6 = __shfl(dv, hb | (k + 6));
            int sv7 = __shfl(sidx, hb | (k + 7)); float f7 = __shfl(dv, hb | (k + 7));
            unsigned p0 = xwp[(size_t)sv0 * 32 + c2];
            unsigned p1 = xwp[(size_t)sv1 * 32 + c2];
            unsigned p2 = xwp[(size_t)sv2 * 32 + c2];
            unsigned p3 = xwp[(size_t)sv3 * 32 + c2];
            unsigned p4 = xwp[(size_t)sv4 * 32 + c2];
            unsigned p5 = xwp[(size_t)sv5 * 32 + c2];
            unsigned p6 = xwp[(size_t)sv6 * 32 + c2];
            unsigned p7 = xwp[(size_t)sv7 * 32 + c2];
            float2 x0 = unpack_bf16x2(p0), x1 = unpack_bf16x2(p1);
            float2 x2 = unpack_bf16x2(p2), x3 = unpack_bf16x2(p3);
            float2 x4 = unpack_bf16x2(p4), x5 = unpack_bf16x2(p5);
            float2 x6 = unpack_bf16x2(p6), x7 = unpack_bf16x2(p7);
            acc0 += x0.x * f0 + x1.x * f1 + x2.x * f2 + x3.x * f3
                  + x4.x * f4 + x5.x * f5 + x6.x * f6 + x7.x * f7;
            acc1 += x0.y * f0 + x1.y * f1 + x2.y * f2 + x3.y * f3
                  + x4.y * f4 + x5.y * f5 + x6.y * f6 + x7.y * f7;
        }
        for (; k < cnt; ++k) {
            int sv = __shfl(sidx, hb | k);
            float fk = __shfl(dv, hb | k);
            float2 xv = unpack_bf16x2(xwp[(size_t)sv * 32 + c2]);
            acc0 += xv.x * fk;
            acc1 += xv.y * fk;
        }
    }
    float2 cbv = *(const float2*)&cb[2 * c2];
    float v0 = acc0 * di + cbv.x;
    float v1 = acc1 * di + cbv.y;
    float s = v0 + v1;
#pragma unroll
    for (int off = 16; off; off >>= 1) s += __shfl_xor(s, off);
    float mu = s * (1.0f / 64.0f);
    float d0 = v0 - mu, d1 = v1 - mu;
    float qq = d0 * d0 + d1 * d1;
#pragma unroll
    for (int off = 16; off; off >>= 1) qq += __shfl_xor(qq, off);
    float r = rsqrtf(qq * (1.0f / 64.0f) + 1e-5f);
    float2 gv = *(const float2*)&g[2 * c2];
    float2 bv = *(const float2*)&b[2 * c2];
    float o0 = fmaxf(d0 * r * gv.x + bv.x, 0.0f);
    float o1 = fmaxf(d1 * r * gv.y + bv.y, 0.0f);
    nt_store_f2(&h[(size_t)node * HDIM + 2 * c2], o0, o1);
}

// ---------------- residual gather: res[s] = sum adj * xw[dst] ----------------
__global__ void res_gather(const unsigned* __restrict__ xwp, const int* __restrict__ rp,
                           const int2* __restrict__ csr, float* __restrict__ res, int n) {
    int gid = blockIdx.x * blockDim.x + threadIdx.x;
    int node = gid >> 5;
    if (node >= n) return;
    int c2 = gid & 31;
    int wl = threadIdx.x & 63;
    int hb = wl & 32;
    int e0 = rp[node], e1 = rp[node + 1];
    float acc0 = 0.0f, acc1 = 0.0f;
    for (int j0 = e0; j0 < e1; j0 += 32) {
        int jj = j0 + c2;
        int didx = 0; float vv = 0.0f;
        if (jj < e1) { int2 pl = nt_load_int2(&csr[jj]); didx = pl.x; vv = __int_as_float(pl.y); }
        int cnt = min(32, e1 - j0);
        int k = 0;
        for (; k + 8 <= cnt; k += 8) {
            int sv0 = __shfl(didx, hb | k);       float f0 = __shfl(vv, hb | k);
            int sv1 = __shfl(didx, hb | (k + 1)); float f1 = __shfl(vv, hb | (k + 1));
            int sv2 = __shfl(didx, hb | (k + 2)); float f2 = __shfl(vv, hb | (k + 2));
            int sv3 = __shfl(didx, hb | (k + 3)); float f3 = __shfl(vv, hb | (k + 3));
            int sv4 = __shfl(didx, hb | (k + 4)); float f4 = __shfl(vv, hb | (k + 4));
            int sv5 = __shfl(didx, hb | (k + 5)); float f5 = __shfl(vv, hb | (k + 5));
            int sv6 = __shfl(didx, hb | (k + 6)); float f6 = __shfl(vv, hb | (k + 6));
            int sv7 = __shfl(didx, hb | (k + 7)); float f7 = __shfl(vv, hb | (k + 7));
            unsigned p0 = xwp[(size_t)sv0 * 32 + c2];
            unsigned p1 = xwp[(size_t)sv1 * 32 + c2];
            unsigned p2 = xwp[(size_t)sv2 * 32 + c2];
            unsigned p3 = xwp[(size_t)sv3 * 32 + c2];
            unsigned p4 = xwp[(size_t)sv4 * 32 + c2];
            unsigned p5 = xwp[(size_t)sv5 * 32 + c2];
            unsigned p6 = xwp[(size_t)sv6 * 32 + c2];
            unsigned p7 = xwp[(size_t)sv7 * 32 + c2];
            float2 x0 = unpack_bf16x2(p0), x1 = unpack_bf16x2(p1);
            float2 x2 = unpack_bf16x2(p2), x3 = unpack_bf16x2(p3);
            float2 x4 = unpack_bf16x2(p4), x5 = unpack_bf16x2(p5);
            float2 x6 = unpack_bf16x2(p6), x7 = unpack_bf16x2(p7);
            acc0 += x0.x * f0 + x1.x * f1 + x2.x * f2 + x3.x * f3
                  + x4.x * f4 + x5.x * f5 + x6.x * f6 + x7.x * f7;
            acc1 += x0.y * f0 + x1.y * f1 + x2.y * f2 + x3.y * f3
                  + x4.y * f4 + x5.y * f5 + x6.y * f6 + x7.y * f7;
        }
        for (; k < cnt; ++k) {
            int dv = __shfl(didx, hb | k);
            float fk = __shfl(vv, hb | k);
            float2 xv = unpack_bf16x2(xwp[(size_t)dv * 32 + c2]);
            acc0 += xv.x * fk;
            acc1 += xv.y * fk;
        }
    }
    nt_store_f2(&res[(size_t)node * HDIM + 2 * c2], acc0, acc1);
}

extern "C" void kernel_launch(void* const* d_in, const int* in_sizes, int n_in,
                              void* d_out, int out_size, void* d_ws, size_t ws_size,
                              hipStream_t stream) {
    const float* x     = (const float*)d_in[0];
    const float* xorg  = (const float*)d_in[1];
    const float* adjv  = (const float*)d_in[2];
    const float* Wi    = (const float*)d_in[3];
    const float* bi    = (const float*)d_in[4];
    const float* convW = (const float*)d_in[5];
    const float* convB = (const float*)d_in[6];
    const float* lng   = (const float*)d_in[7];
    const float* lnb   = (const float*)d_in[8];
    const float* Wl    = (const float*)d_in[9];
    const float* bl    = (const float*)d_in[10];
    const float* Wres  = (const float*)d_in[11];
    const int*   ei    = (const int*)d_in[12];
    const int* src = ei;
    const int* dst = ei + NEDGES;

    float* out = (float*)d_out;               // [N,64]
    float* res = out + (size_t)NNODES * HDIM; // [N,64]

    // ---- workspace layout ----
    float* h      = (float*)d_ws;                           // N*64 f32
    unsigned* xwp = (unsigned*)(h + (size_t)NNODES * HDIM); // N*32 u32
    float* dinv   = (float*)(xwp + (size_t)NNODES * 32);    // N
    int* cnt_d    = (int*)(dinv + NNODES);              // N
    int* cnt_s    = cnt_d + NNODES;                     // N
    int* rp_d     = cnt_s + NNODES;                     // N+1
    int* rp_s     = rp_d + (NNODES + 1);                // N+1
    int* cur_d    = rp_s + (NNODES + 1);                // N
    int* cur_s    = cur_d + NNODES;                     // N
    int* bsum_d   = cur_s + NNODES;                     // 256
    int* boff_d   = bsum_d + 256;                       // 256
    int* bsum_s   = boff_d + 256;                       // 256
    int* boff_s   = bsum_s + 256;                       // 256
    size_t ofs = (size_t)(boff_s + 256 - (int*)d_ws);
    ofs = (ofs + 1) & ~(size_t)1;
    int2* csr_d = (int2*)((int*)d_ws + ofs);            // E int2
    int2* csr_s = csr_d + NEDGES;                       // E int2

    const int ngrid1 = (NNODES + 255) / 256;
    const int ngrid32 = (NNODES * 32 + 255) / 256;

    // ---- CSR build ----
    hipMemsetAsync(cnt_d, 0, 2 * (size_t)NNODES * sizeof(int), stream);
    hist4<<<(NEDGES / 4 + 255) / 256, 256, 0, stream>>>(
        (const int4*)src, (const int4*)dst, cnt_s, cnt_d, NEDGES / 4);
    make_dinv<<<ngrid1, 256, 0, stream>>>(cnt_d, dinv, NNODES);

    scan1<<<NBLK_SCAN, SCAN_BS, 0, stream>>>(cnt_d, rp_d, bsum_d, NNODES);
    scan1<<<NBLK_SCAN, SCAN_BS, 0, stream>>>(cnt_s, rp_s, bsum_s, NNODES);
    scan2<<<1, 256, 0, stream>>>(bsum_d, boff_d, NBLK_SCAN);
    scan2<<<1, 256, 0, stream>>>(bsum_s, boff_s, NBLK_SCAN);
    scan3<<<ngrid1, 256, 0, stream>>>(rp_d, cur_d, boff_d, NNODES, NEDGES);
    scan3<<<ngrid1, 256, 0, stream>>>(rp_s, cur_s, boff_s, NNODES, NEDGES);
    fill_csr_part<<<2048, 256, 0, stream>>>(src, dst, adjv, dinv, cur_d, cur_s,
                                            csr_d, csr_s, NEDGES);

    // ---- h0 = relu(x @ Wi + bi) ----
    gemm64<<<2048, 256, 0, stream>>>(x, Wi, bi, h, NNODES, 1);

    // ---- residual = gather_src(adj * (x_org @ Wres)[dst]) ----
    gemm64p<<<2048, 256, 0, stream>>>(xorg, Wres, xwp, NNODES);
    res_gather<<<ngrid32, 256, 0, stream>>>(xwp, rp_s, csr_s, res, NNODES);

    // ---- 3 GCN layers: packed gemm -> fused gather+LN+ReLU ----
    for (int l = 0; l < 3; ++l) {
        gemm64p<<<2048, 256, 0, stream>>>(h, convW + l * HDIM * HDIM, xwp, NNODES);
        conv_ln<<<ngrid32, 256, 0, stream>>>(xwp, rp_d, csr_d, dinv,
                                             convB + l * HDIM, lng + l * HDIM,
                                             lnb + l * HDIM, h, NNODES);
    }

    // ---- out = h @ Wl + bl ----
    gemm64<<<2048, 256, 0, stream>>>(h, Wl, bl, out, NNODES, 0);
}

// Round 8
// 593.476 us; speedup vs baseline: 1.0587x; 1.0587x over previous
//
#include <hip/hip_runtime.h>

#define NNODES 100000
#define NEDGES 1600000
#define HDIM 64
#define SCAN_BS 512
#define NBLK_SCAN ((NNODES + SCAN_BS - 1) / SCAN_BS)   // 196
#define NPART 8
#define PRANGE 12500   // NNODES / NPART exactly

// ---------- bf16x2 pack/unpack (RNE pack; exact unpack) ----------
__device__ inline unsigned pack_bf16x2(float a, float b) {
    union { float f; unsigned u; } ua, ub;
    ua.f = a; ub.f = b;
    unsigned ra = (ua.u + 0x7FFFu + ((ua.u >> 16) & 1u)) >> 16;
    unsigned rb = (ub.u + 0x7FFFu + ((ub.u >> 16) & 1u)) >> 16;
    return ra | (rb << 16);
}
__device__ inline float2 unpack_bf16x2(unsigned p) {
    union { unsigned u; float f; } a, b;
    a.u = p << 16;
    b.u = p & 0xFFFF0000u;
    return make_float2(a.f, b.f);
}

// ---------------- CSR build: histogram (4 edges/thread) ----------------
__global__ void hist4(const int4* __restrict__ src4, const int4* __restrict__ dst4,
                      int* cnt_s, int* cnt_d, int ne4) {
    int i = blockIdx.x * blockDim.x + threadIdx.x;
    if (i >= ne4) return;
    int4 s = src4[i], d = dst4[i];
    atomicAdd(&cnt_s[s.x], 1); atomicAdd(&cnt_s[s.y], 1);
    atomicAdd(&cnt_s[s.z], 1); atomicAdd(&cnt_s[s.w], 1);
    atomicAdd(&cnt_d[d.x], 1); atomicAdd(&cnt_d[d.y], 1);
    atomicAdd(&cnt_d[d.z], 1); atomicAdd(&cnt_d[d.w], 1);
}

__global__ void make_dinv(const int* __restrict__ cnt_d, float* dinv, int n) {
    int i = blockIdx.x * blockDim.x + threadIdx.x;
    if (i < n) dinv[i] = rsqrtf((float)(cnt_d[i] + 1));   // +1 self-loop
}

// ---------------- CSR build: 2-level exclusive scan ----------------
__global__ void scan1(const int* __restrict__ cnt, int* rp, int* bsum, int n) {
    __shared__ int temp[SCAN_BS];
    int tid = threadIdx.x;
    int i = blockIdx.x * SCAN_BS + tid;
    int v = (i < n) ? cnt[i] : 0;
    temp[tid] = v;
    __syncthreads();
    for (int off = 1; off < SCAN_BS; off <<= 1) {
        int t = (tid >= off) ? temp[tid - off] : 0;
        __syncthreads();
        temp[tid] += t;
        __syncthreads();
    }
    int inc = temp[tid];
    if (i < n) rp[i] = inc - v;
    if (tid == SCAN_BS - 1) bsum[blockIdx.x] = inc;
}

__global__ void scan2(const int* __restrict__ bsum, int* boff, int nb) {
    __shared__ int temp[256];
    int tid = threadIdx.x;
    int v = (tid < nb) ? bsum[tid] : 0;
    temp[tid] = v;
    __syncthreads();
    for (int off = 1; off < 256; off <<= 1) {
        int t = (tid >= off) ? temp[tid - off] : 0;
        __syncthreads();
        temp[tid] += t;
        __syncthreads();
    }
    if (tid < nb) boff[tid] = temp[tid] - v;
}

__global__ void scan3(int* rp, int* cur, const int* __restrict__ boff, int n, int total) {
    int i = blockIdx.x * blockDim.x + threadIdx.x;
    if (i < n) {
        int v = rp[i] + boff[i / SCAN_BS];
        rp[i] = v;
        cur[i] = v;
    }
    if (i == 0) rp[n] = total;
}

// ---------------- CSR fill, XCD-partitioned scatter ----------------
// dst-CSR entry: src (4B).  src-CSR payload: (dst, adjv) (8B).
__global__ void fill_csr_part(const int* __restrict__ src, const int* __restrict__ dst,
                              const float* __restrict__ adjv,
                              int* cur_d, int* cur_s,
                              int* __restrict__ csr_d, int2* __restrict__ csr_s, int ne) {
    int part = blockIdx.x & (NPART - 1);
    int blk  = blockIdx.x >> 3;
    int nblk = gridDim.x >> 3;
    int lo = part * PRANGE;
    for (int i = blk * blockDim.x + threadIdx.x; i < ne; i += nblk * blockDim.x) {
        int s = src[i], d = dst[i];
        if ((unsigned)(d - lo) < PRANGE) {
            int p = atomicAdd(&cur_d[d], 1);
            csr_d[p] = s;
        }
        if ((unsigned)(s - lo) < PRANGE) {
            int2 ps; ps.x = d; ps.y = __float_as_int(adjv[i]);
            int q = atomicAdd(&cur_s[s], 1);
            csr_s[q] = ps;
        }
    }
}

// ---------------- GEMM [n,64]@[64,64] -> f32 (+bias, optional relu) ----------------
__global__ void gemm64(const float* __restrict__ X, const float* __restrict__ W,
                       const float* __restrict__ bias, float* __restrict__ Y,
                       int n, int do_relu) {
    __shared__ float Ws[HDIM * HDIM];
    __shared__ float xs[16][68];
    int tid = threadIdx.x;
    for (int i = tid; i < HDIM * HDIM; i += 256) Ws[i] = W[i];
    int q = tid & 15;
    int rl = tid >> 4;
    float4 bc = bias ? *(const float4*)&bias[4 * q] : make_float4(0.f, 0.f, 0.f, 0.f);
    __syncthreads();
    for (int r0 = blockIdx.x * 16; r0 < n; r0 += gridDim.x * 16) {
        int r = r0 + rl;
        if (r < n) {
            *(float4*)&xs[rl][4 * q] = *(const float4*)&X[(size_t)r * HDIM + 4 * q];
            float4 acc = bc;
#pragma unroll
            for (int k = 0; k < HDIM; ++k) {
                float xk = xs[rl][k];
                float4 w4 = *(const float4*)&Ws[k * HDIM + 4 * q];
                acc.x += xk * w4.x; acc.y += xk * w4.y;
                acc.z += xk * w4.z; acc.w += xk * w4.w;
            }
            if (do_relu) {
                acc.x = fmaxf(acc.x, 0.f); acc.y = fmaxf(acc.y, 0.f);
                acc.z = fmaxf(acc.z, 0.f); acc.w = fmaxf(acc.w, 0.f);
            }
            *(float4*)&Y[(size_t)r * HDIM + 4 * q] = acc;
        }
    }
}

// ---------------- GEMM [n,64]@[64,64] -> packed bf16x2 out ----------------
__global__ void gemm64p(const float* __restrict__ X, const float* __restrict__ W,
                        unsigned* __restrict__ Yp, int n) {
    __shared__ float Ws[HDIM * HDIM];
    __shared__ float xs[16][68];
    int tid = threadIdx.x;
    for (int i = tid; i < HDIM * HDIM; i += 256) Ws[i] = W[i];
    int q = tid & 15;
    int rl = tid >> 4;
    __syncthreads();
    for (int r0 = blockIdx.x * 16; r0 < n; r0 += gridDim.x * 16) {
        int r = r0 + rl;
        if (r < n) {
            *(float4*)&xs[rl][4 * q] = *(const float4*)&X[(size_t)r * HDIM + 4 * q];
            float4 acc = make_float4(0.f, 0.f, 0.f, 0.f);
#pragma unroll
            for (int k = 0; k < HDIM; ++k) {
                float xk = xs[rl][k];
                float4 w4 = *(const float4*)&Ws[k * HDIM + 4 * q];
                acc.x += xk * w4.x; acc.y += xk * w4.y;
                acc.z += xk * w4.z; acc.w += xk * w4.w;
            }
            uint2 pv;
            pv.x = pack_bf16x2(acc.x, acc.y);
            pv.y = pack_bf16x2(acc.z, acc.w);
            *(uint2*)&Yp[(size_t)r * 32 + 2 * q] = pv;
        }
    }
}

// ---------------- fused GCN gather + bias + LN + ReLU ----------------
// half-wave (32 lanes) per node; csr_d entry = src only; dinv via broadcast
// load (400 KB, L2-hot, same-address across half-wave); 16-wide unroll.
__global__ void conv_ln(const unsigned* __restrict__ xwp, const int* __restrict__ rp,
                        const int* __restrict__ csr, const float* __restrict__ dinv,
                        const float* __restrict__ cb, const float* __restrict__ g,
                        const float* __restrict__ b, float* __restrict__ h, int n) {
    int gid = blockIdx.x * blockDim.x + threadIdx.x;
    int node = gid >> 5;
    if (node >= n) return;
    int c2 = gid & 31;
    int wl = threadIdx.x & 63;
    int hb = wl & 32;
    int e0 = rp[node], e1 = rp[node + 1];
    float di = dinv[node];
    float2 self = unpack_bf16x2(xwp[(size_t)node * 32 + c2]);
    float acc0 = self.x * di, acc1 = self.y * di;
    for (int j0 = e0; j0 < e1; j0 += 32) {
        int jj = j0 + c2;
        int sidx = (jj < e1) ? csr[jj] : 0;
        int cnt = min(32, e1 - j0);
        int k = 0;
        for (; k + 16 <= cnt; k += 16) {
            int sv[16]; unsigned p[16]; float dv[16];
#pragma unroll
            for (int u = 0; u < 16; ++u) sv[u] = __shfl(sidx, hb | (k + u));
#pragma unroll
            for (int u = 0; u < 16; ++u) {
                p[u] = xwp[(size_t)sv[u] * 32 + c2];
                dv[u] = dinv[sv[u]];
            }
#pragma unroll
            for (int u = 0; u < 16; ++u) {
                float2 xv = unpack_bf16x2(p[u]);
                acc0 += xv.x * dv[u];
                acc1 += xv.y * dv[u];
            }
        }
        for (; k + 8 <= cnt; k += 8) {
            int sv[8]; unsigned p[8]; float dv[8];
#pragma unroll
            for (int u = 0; u < 8; ++u) sv[u] = __shfl(sidx, hb | (k + u));
#pragma unroll
            for (int u = 0; u < 8; ++u) {
                p[u] = xwp[(size_t)sv[u] * 32 + c2];
                dv[u] = dinv[sv[u]];
            }
#pragma unroll
            for (int u = 0; u < 8; ++u) {
                float2 xv = unpack_bf16x2(p[u]);
                acc0 += xv.x * dv[u];
                acc1 += xv.y * dv[u];
            }
        }
        for (; k < cnt; ++k) {
            int sv = __shfl(sidx, hb | k);
            float dvk = dinv[sv];
            float2 xv = unpack_bf16x2(xwp[(size_t)sv * 32 + c2]);
            acc0 += xv.x * dvk;
            acc1 += xv.y * dvk;
        }
    }
    float2 cbv = *(const float2*)&cb[2 * c2];
    float v0 = acc0 * di + cbv.x;
    float v1 = acc1 * di + cbv.y;
    float s = v0 + v1;
#pragma unroll
    for (int off = 16; off; off >>= 1) s += __shfl_xor(s, off);
    float mu = s * (1.0f / 64.0f);
    float d0 = v0 - mu, d1 = v1 - mu;
    float qq = d0 * d0 + d1 * d1;
#pragma unroll
    for (int off = 16; off; off >>= 1) qq += __shfl_xor(qq, off);
    float r = rsqrtf(qq * (1.0f / 64.0f) + 1e-5f);
    float2 gv = *(const float2*)&g[2 * c2];
    float2 bv = *(const float2*)&b[2 * c2];
    float o0 = fmaxf(d0 * r * gv.x + bv.x, 0.0f);
    float o1 = fmaxf(d1 * r * gv.y + bv.y, 0.0f);
    *(float2*)&h[(size_t)node * HDIM + 2 * c2] = make_float2(o0, o1);
}

// ---------------- residual gather: res[s] = sum adj * xw[dst] ----------------
__global__ void res_gather(const unsigned* __restrict__ xwp, const int* __restrict__ rp,
                           const int2* __restrict__ csr, float* __restrict__ res, int n) {
    int gid = blockIdx.x * blockDim.x + threadIdx.x;
    int node = gid >> 5;
    if (node >= n) return;
    int c2 = gid & 31;
    int wl = threadIdx.x & 63;
    int hb = wl & 32;
    int e0 = rp[node], e1 = rp[node + 1];
    float acc0 = 0.0f, acc1 = 0.0f;
    for (int j0 = e0; j0 < e1; j0 += 32) {
        int jj = j0 + c2;
        int didx = 0; float vv = 0.0f;
        if (jj < e1) { int2 pl = csr[jj]; didx = pl.x; vv = __int_as_float(pl.y); }
        int cnt = min(32, e1 - j0);
        int k = 0;
        for (; k + 16 <= cnt; k += 16) {
            int sv[16]; float f[16]; unsigned p[16];
#pragma unroll
            for (int u = 0; u < 16; ++u) {
                sv[u] = __shfl(didx, hb | (k + u));
                f[u] = __shfl(vv, hb | (k + u));
            }
#pragma unroll
            for (int u = 0; u < 16; ++u) p[u] = xwp[(size_t)sv[u] * 32 + c2];
#pragma unroll
            for (int u = 0; u < 16; ++u) {
                float2 xv = unpack_bf16x2(p[u]);
                acc0 += xv.x * f[u];
                acc1 += xv.y * f[u];
            }
        }
        for (; k + 8 <= cnt; k += 8) {
            int sv[8]; float f[8]; unsigned p[8];
#pragma unroll
            for (int u = 0; u < 8; ++u) {
                sv[u] = __shfl(didx, hb | (k + u));
                f[u] = __shfl(vv, hb | (k + u));
            }
#pragma unroll
            for (int u = 0; u < 8; ++u) p[u] = xwp[(size_t)sv[u] * 32 + c2];
#pragma unroll
            for (int u = 0; u < 8; ++u) {
                float2 xv = unpack_bf16x2(p[u]);
                acc0 += xv.x * f[u];
                acc1 += xv.y * f[u];
            }
        }
        for (; k < cnt; ++k) {
            int dv = __shfl(didx, hb | k);
            float fk = __shfl(vv, hb | k);
            float2 xv = unpack_bf16x2(xwp[(size_t)dv * 32 + c2]);
            acc0 += xv.x * fk;
            acc1 += xv.y * fk;
        }
    }
    *(float2*)&res[(size_t)node * HDIM + 2 * c2] = make_float2(acc0, acc1);
}

extern "C" void kernel_launch(void* const* d_in, const int* in_sizes, int n_in,
                              void* d_out, int out_size, void* d_ws, size_t ws_size,
                              hipStream_t stream) {
    const float* x     = (const float*)d_in[0];
    const float* xorg  = (const float*)d_in[1];
    const float* adjv  = (const float*)d_in[2];
    const float* Wi    = (const float*)d_in[3];
    const float* bi    = (const float*)d_in[4];
    const float* convW = (const float*)d_in[5];
    const float* convB = (const float*)d_in[6];
    const float* lng   = (const float*)d_in[7];
    const float* lnb   = (const float*)d_in[8];
    const float* Wl    = (const float*)d_in[9];
    const float* bl    = (const float*)d_in[10];
    const float* Wres  = (const float*)d_in[11];
    const int*   ei    = (const int*)d_in[12];
    const int* src = ei;
    const int* dst = ei + NEDGES;

    float* out = (float*)d_out;               // [N,64]
    float* res = out + (size_t)NNODES * HDIM; // [N,64]

    // ---- workspace layout ----
    float* h      = (float*)d_ws;                           // N*64 f32
    unsigned* xwp = (unsigned*)(h + (size_t)NNODES * HDIM); // N*32 u32
    float* dinv   = (float*)(xwp + (size_t)NNODES * 32);    // N
    int* cnt_d    = (int*)(dinv + NNODES);              // N
    int* cnt_s    = cnt_d + NNODES;                     // N
    int* rp_d     = cnt_s + NNODES;                     // N+1
    int* rp_s     = rp_d + (NNODES + 1);                // N+1
    int* cur_d    = rp_s + (NNODES + 1);                // N
    int* cur_s    = cur_d + NNODES;                     // N
    int* bsum_d   = cur_s + NNODES;                     // 256
    int* boff_d   = bsum_d + 256;                       // 256
    int* bsum_s   = boff_d + 256;                       // 256
    int* boff_s   = bsum_s + 256;                       // 256
    size_t ofs = (size_t)(boff_s + 256 - (int*)d_ws);
    ofs = (ofs + 1) & ~(size_t)1;
    int* csr_d = (int*)d_ws + ofs;                      // E int (4B entries)
    int2* csr_s = (int2*)(csr_d + NEDGES);              // E int2 (8B-aligned: E even)

    const int ngrid1 = (NNODES + 255) / 256;
    const int ngrid32 = (NNODES * 32 + 255) / 256;

    // ---- CSR build ----
    hipMemsetAsync(cnt_d, 0, 2 * (size_t)NNODES * sizeof(int), stream);
    hist4<<<(NEDGES / 4 + 255) / 256, 256, 0, stream>>>(
        (const int4*)src, (const int4*)dst, cnt_s, cnt_d, NEDGES / 4);
    make_dinv<<<ngrid1, 256, 0, stream>>>(cnt_d, dinv, NNODES);

    scan1<<<NBLK_SCAN, SCAN_BS, 0, stream>>>(cnt_d, rp_d, bsum_d, NNODES);
    scan1<<<NBLK_SCAN, SCAN_BS, 0, stream>>>(cnt_s, rp_s, bsum_s, NNODES);
    scan2<<<1, 256, 0, stream>>>(bsum_d, boff_d, NBLK_SCAN);
    scan2<<<1, 256, 0, stream>>>(bsum_s, boff_s, NBLK_SCAN);
    scan3<<<ngrid1, 256, 0, stream>>>(rp_d, cur_d, boff_d, NNODES, NEDGES);
    scan3<<<ngrid1, 256, 0, stream>>>(rp_s, cur_s, boff_s, NNODES, NEDGES);
    fill_csr_part<<<2048, 256, 0, stream>>>(src, dst, adjv, cur_d, cur_s,
                                            csr_d, csr_s, NEDGES);

    // ---- h0 = relu(x @ Wi + bi) ----
    gemm64<<<2048, 256, 0, stream>>>(x, Wi, bi, h, NNODES, 1);

    // ---- residual = gather_src(adj * (x_org @ Wres)[dst]) ----
    gemm64p<<<2048, 256, 0, stream>>>(xorg, Wres, xwp, NNODES);
    res_gather<<<ngrid32, 256, 0, stream>>>(xwp, rp_s, csr_s, res, NNODES);

    // ---- 3 GCN layers: packed gemm -> fused gather+LN+ReLU ----
    for (int l = 0; l < 3; ++l) {
        gemm64p<<<2048, 256, 0, stream>>>(h, convW + l * HDIM * HDIM, xwp, NNODES);
        conv_ln<<<ngrid32, 256, 0, stream>>>(xwp, rp_d, csr_d, dinv,
                                             convB + l * HDIM, lng + l * HDIM,
                                             lnb + l * HDIM, h, NNODES);
    }

    // ---- out = h @ Wl + bl ----
    gemm64<<<2048, 256, 0, stream>>>(h, Wl, bl, out, NNODES, 0);
}